// Round 6
// baseline (195.558 us; speedup 1.0000x reference)
//
#include <hip/hip_runtime.h>

#define NL 30
#define RPB 512              // rows per block (2 rows/thread, 256 threads)

// Native ext-vector types: accepted by __builtin_nontemporal_store
// (HIP_vector_type float2 class is NOT — R5 compile failure).
typedef float v2f __attribute__((ext_vector_type(2)));
typedef float v4f __attribute__((ext_vector_type(4)));

static __device__ __forceinline__ v2f flo(v4f v) { v2f r; r.x = v.x; r.y = v.y; return r; }
static __device__ __forceinline__ v2f fhi(v4f v) { v2f r; r.x = v.z; r.y = v.w; return r; }
static __device__ __forceinline__ v2f vrelu(v2f a) {
    v2f r; r.x = fmaxf(a.x, 0.f); r.y = fmaxf(a.y, 0.f); return r;
}
static __device__ __forceinline__ v2f vfma(v2f a, v2f b, v2f c) {
    return __builtin_elementwise_fma(a, b, c);   // -> v_pk_fma_f32
}

// R4 theory: kill transaction amplification. x2/o2 rows are 20B -> any direct
// per-row global access fragments each wave instruction into 4-5x the ideal
// L2 transaction count (R0..R3 all share this; all land at ~72us).
// Fix: stage the block's 10KB x2 slab through LDS:
//   global v2f lane-contiguous (512B/instr, perfectly coalesced)
//   -> LDS -> per-row reads at stride 5 dwords (conflict-free: 5*dl%32=0 only
//   at dl=32 -> 2 lanes/bank = free). Reverse for o2, nt stores.
// 2 rows/thread -> 8192 blocks (occupancy was 72% at high block count vs
// 55-59% at 4096).
__global__ __launch_bounds__(256) void drn_kernel(
    const float* __restrict__ x1, const float* __restrict__ x2,
    const float* __restrict__ W1, const float* __restrict__ b1,
    const float* __restrict__ W2,
    float* __restrict__ o1, float* __restrict__ o2)
{
    __shared__ __align__(16) float sp[NL * 24];
    __shared__ __align__(16) float slab[RPB * 5];   // 10 KB

    // Params pre-duplicated as {w,w} pairs: one ds_read_b128 = two packed operands.
    for (int i = threadIdx.x; i < NL * 24; i += 256) {
        int p = i >> 1, l = p / 12, k = p % 12;
        float v = 0.0f;
        if (k < 5)        v = W1[l * 5 + k];
        else if (k == 5)  v = b1[l];
        else if (k < 11)  v = W2[l * 5 + (k - 6)];
        sp[i] = v;
    }

    const int t = threadIdx.x;
    const int base = blockIdx.x * RPB;              // first row of this block

    // x1: rows (base+t, base+256+t) -> two coalesced dword loads.
    v2f h1;
    h1.x = x1[base + t];
    h1.y = x1[base + 256 + t];

    // Stage x2 slab: 2560 floats = 1280 v2f; thread t moves v2f t+256k.
    const v2f* g2 = (const v2f*)(x2 + (size_t)base * 5);
    v2f* s2 = (v2f*)slab;
    #pragma unroll
    for (int k = 0; k < 5; ++k)
        s2[t + 256 * k] = g2[t + 256 * k];
    __syncthreads();

    // Rows t and t+256 (slab-local), packed into v2f pairs.
    v2f h2[5];
    #pragma unroll
    for (int j = 0; j < 5; ++j) {
        h2[j].x = slab[5 * t + j];
        h2[j].y = slab[5 * t + 1280 + j];
    }

    const v4f* spv = (const v4f*)sp;
    #pragma unroll
    for (int l = 0; l < NL; ++l) {
        const v4f L0 = spv[l * 6 + 0];
        const v4f L1 = spv[l * 6 + 1];
        const v4f L2 = spv[l * 6 + 2];
        const v4f L3 = spv[l * 6 + 3];
        const v4f L4 = spv[l * 6 + 4];
        const v4f L5 = spv[l * 6 + 5];
        const v2f w10 = flo(L0), w11 = fhi(L0), w12 = flo(L1), w13 = fhi(L1),
                  w14 = flo(L2), vbb = fhi(L2),
                  w20 = flo(L3), w21 = fhi(L3), w22 = flo(L4), w23 = fhi(L4),
                  w24 = flo(L5);

        v2f s = h1 + vbb;
        s = vfma(vrelu(h2[0]), w10, s);
        s = vfma(vrelu(h2[1]), w11, s);
        s = vfma(vrelu(h2[2]), w12, s);
        s = vfma(vrelu(h2[3]), w13, s);
        s = vfma(vrelu(h2[4]), w14, s);
        h1 = s;
        const v2f rh = vrelu(s);
        h2[0] = vfma(rh, w20, h2[0]);
        h2[1] = vfma(rh, w21, h2[1]);
        h2[2] = vfma(rh, w22, h2[2]);
        h2[3] = vfma(rh, w23, h2[3]);
        h2[4] = vfma(rh, w24, h2[4]);
    }

    // o1: two coalesced dword stores.
    __builtin_nontemporal_store(h1.x, &o1[base + t]);
    __builtin_nontemporal_store(h1.y, &o1[base + 256 + t]);

    // o2 via LDS transpose back to lane-contiguous v2f stores.
    __syncthreads();   // all slab reads (pre-compute) complete before overwrite
    #pragma unroll
    for (int j = 0; j < 5; ++j) {
        slab[5 * t + j]        = h2[j].x;
        slab[5 * t + 1280 + j] = h2[j].y;
    }
    __syncthreads();
    v2f* go2 = (v2f*)(o2 + (size_t)base * 5);
    #pragma unroll
    for (int k = 0; k < 5; ++k)
        __builtin_nontemporal_store(s2[t + 256 * k], &go2[t + 256 * k]);
}

extern "C" void kernel_launch(void* const* d_in, const int* in_sizes, int n_in,
                              void* d_out, int out_size, void* d_ws, size_t ws_size,
                              hipStream_t stream) {
    const float* x1 = (const float*)d_in[0];
    const float* x2 = (const float*)d_in[1];
    const float* W1 = (const float*)d_in[2];
    const float* b1 = (const float*)d_in[3];
    const float* W2 = (const float*)d_in[4];
    int nrows = in_sizes[0];            // 4,194,304
    float* o1 = (float*)d_out;          // [nrows]
    float* o2 = (float*)d_out + nrows;  // [nrows*5]

    int block = 256;
    int grid = nrows / RPB;             // 8192 blocks, 2 rows/thread
    drn_kernel<<<grid, block, 0, stream>>>(x1, x2, W1, b1, W2, o1, o2);
}

// Round 7
// 188.548 us; speedup vs baseline: 1.0372x; 1.0372x over previous
//
#include <hip/hip_runtime.h>

#define NL 30
#define RPB 512              // rows per block (2 rows/thread, 256 threads)

// v2f only for staging (native ext-vector works with nontemporal builtin).
typedef float v2f __attribute__((ext_vector_type(2)));

// R7: scalar core with direct-SGPR weight operands.
// Ladder so far: R1 (s_load+packed) stalled on 22 splat-movs/layer (VALU 37us);
// R6 (LDS pre-dup+packed) pays 6 ds_read_b128/layer on the LDS pipe (VALU 43us,
// dur 67us). Both are param-DELIVERY overhead. Scalar v_fma_f32 v,v,s,v reads
// the uniform weight straight from SGPR: no movs, no ds_reads, 1 SGPR/instr
// (legal). v_pk gives no VALU-time gain anyway (4 issue cyc vs 2x2 — fp32 peak
// assumes unpacked), so dropping it costs nothing.
// VALU floor: 17 instr/row/layer * 2 rows * 2cyc = 68 cyc/wave/layer
//             -> 27us chip-wide at 32 waves/SIMD. Mem floor ~24us.
__global__ __launch_bounds__(256) void drn_kernel(
    const float* __restrict__ x1, const float* __restrict__ x2,
    const float* __restrict__ W1, const float* __restrict__ b1,
    const float* __restrict__ W2,
    float* __restrict__ o1, float* __restrict__ o2)
{
    __shared__ __align__(16) float slab[RPB * 5];   // 10 KB

    const int t = threadIdx.x;
    const int base = blockIdx.x * RPB;

    // Stage x2 slab: lane-contiguous v2f (512B/instr, zero amplification).
    const v2f* g2 = (const v2f*)(x2 + (size_t)base * 5);
    v2f* s2 = (v2f*)slab;
    #pragma unroll
    for (int k = 0; k < 5; ++k)
        s2[t + 256 * k] = g2[t + 256 * k];

    float h1x = x1[base + t];
    float h1y = x1[base + 256 + t];

    __syncthreads();

    // Rows t and t+256, slab-local (stride-5 dword reads: conflict-free).
    float h2x[5], h2y[5];
    #pragma unroll
    for (int j = 0; j < 5; ++j) {
        h2x[j] = slab[5 * t + j];
        h2y[j] = slab[5 * t + 1280 + j];
    }

    #pragma unroll
    for (int l = 0; l < NL; ++l) {
        // Uniform scalar loads -> SGPRs (compiler prefetches across unroll;
        // 1.4KB of params is scalar-L1-resident after the first wave).
        const float w10 = W1[l * 5 + 0], w11 = W1[l * 5 + 1], w12 = W1[l * 5 + 2],
                    w13 = W1[l * 5 + 3], w14 = W1[l * 5 + 4];
        const float bb  = b1[l];
        const float w20 = W2[l * 5 + 0], w21 = W2[l * 5 + 1], w22 = W2[l * 5 + 2],
                    w23 = W2[l * 5 + 3], w24 = W2[l * 5 + 4];

        // row x
        {
            float s = h1x + bb;
            s = fmaf(fmaxf(h2x[0], 0.f), w10, s);
            s = fmaf(fmaxf(h2x[1], 0.f), w11, s);
            s = fmaf(fmaxf(h2x[2], 0.f), w12, s);
            s = fmaf(fmaxf(h2x[3], 0.f), w13, s);
            s = fmaf(fmaxf(h2x[4], 0.f), w14, s);
            h1x = s;
            const float rh = fmaxf(s, 0.f);
            h2x[0] = fmaf(rh, w20, h2x[0]);
            h2x[1] = fmaf(rh, w21, h2x[1]);
            h2x[2] = fmaf(rh, w22, h2x[2]);
            h2x[3] = fmaf(rh, w23, h2x[3]);
            h2x[4] = fmaf(rh, w24, h2x[4]);
        }
        // row y
        {
            float s = h1y + bb;
            s = fmaf(fmaxf(h2y[0], 0.f), w10, s);
            s = fmaf(fmaxf(h2y[1], 0.f), w11, s);
            s = fmaf(fmaxf(h2y[2], 0.f), w12, s);
            s = fmaf(fmaxf(h2y[3], 0.f), w13, s);
            s = fmaf(fmaxf(h2y[4], 0.f), w14, s);
            h1y = s;
            const float rh = fmaxf(s, 0.f);
            h2y[0] = fmaf(rh, w20, h2y[0]);
            h2y[1] = fmaf(rh, w21, h2y[1]);
            h2y[2] = fmaf(rh, w22, h2y[2]);
            h2y[3] = fmaf(rh, w23, h2y[3]);
            h2y[4] = fmaf(rh, w24, h2y[4]);
        }
    }

    __builtin_nontemporal_store(h1x, &o1[base + t]);
    __builtin_nontemporal_store(h1y, &o1[base + 256 + t]);

    // o2 via LDS transpose back to lane-contiguous v2f nt stores.
    __syncthreads();   // all slab reads complete before overwrite
    #pragma unroll
    for (int j = 0; j < 5; ++j) {
        slab[5 * t + j]        = h2x[j];
        slab[5 * t + 1280 + j] = h2y[j];
    }
    __syncthreads();
    v2f* go2 = (v2f*)(o2 + (size_t)base * 5);
    #pragma unroll
    for (int k = 0; k < 5; ++k)
        __builtin_nontemporal_store(s2[t + 256 * k], &go2[t + 256 * k]);
}

extern "C" void kernel_launch(void* const* d_in, const int* in_sizes, int n_in,
                              void* d_out, int out_size, void* d_ws, size_t ws_size,
                              hipStream_t stream) {
    const float* x1 = (const float*)d_in[0];
    const float* x2 = (const float*)d_in[1];
    const float* W1 = (const float*)d_in[2];
    const float* b1 = (const float*)d_in[3];
    const float* W2 = (const float*)d_in[4];
    int nrows = in_sizes[0];            // 4,194,304
    float* o1 = (float*)d_out;          // [nrows]
    float* o2 = (float*)d_out + nrows;  // [nrows*5]

    int block = 256;
    int grid = nrows / RPB;             // 8192 blocks, 2 rows/thread
    drn_kernel<<<grid, block, 0, stream>>>(x1, x2, W1, b1, W2, o1, o2);
}